// Round 5
// baseline (1665.151 us; speedup 1.0000x reference)
//
#include <hip/hip_runtime.h>
#include <hip/hip_bf16.h>

#define NEG_SLOPE 0.01f

typedef long long i64;
typedef __hip_bfloat16 bf16;

__device__ __forceinline__ float lrelu(float x) { return x > 0.f ? x : NEG_SLOPE * x; }
__device__ __forceinline__ float b2f(bf16 v) { return __bfloat162float(v); }

// ================= degree (batch-independent) =================
__global__ __launch_bounds__(256) void k_deg(const int* __restrict__ edges,
                                             int* __restrict__ indeg, int E) {
    int e = blockIdx.x * 256 + threadIdx.x;
    if (e < E) atomicAdd(&indeg[edges[2 * e + 1]], 1);
}

__global__ __launch_bounds__(256) void k_dinv(const int* __restrict__ indeg,
                                              float* __restrict__ dinv, int V) {
    int v = blockIdx.x * 256 + threadIdx.x;
    if (v < V) dinv[v] = rsqrtf((float)indeg[v] + 1.0f);
}

// ================= specialized H == 16 path =================
__global__ __launch_bounds__(256) void k_l1_16(const float* __restrict__ x,
                                               const float* __restrict__ W1,
                                               const float* __restrict__ dinv,
                                               bf16* __restrict__ P, float* __restrict__ Q,
                                               int b0, int V) {
    __shared__ float sW[48];
    if (threadIdx.x < 48) sW[threadIdx.x] = W1[threadIdx.x];
    __syncthreads();
    int v = blockIdx.x * 256 + threadIdx.x;
    if (v >= V) return;
    i64 n = (i64)(b0 + blockIdx.y) * V + v;   // global row (input)
    i64 m = (i64)blockIdx.y * V + v;          // local row (workspace)
    float di = dinv[v];
    float x0 = x[n * 3], x1 = x[n * 3 + 1], x2 = x[n * 3 + 2];
    float g[16];
#pragma unroll
    for (int f = 0; f < 16; ++f)
        g[f] = di * (x0 * sW[f] + x1 * sW[16 + f] + x2 * sW[32 + f]);
    bf16* Pp = P + m * 16;
#pragma unroll
    for (int f = 0; f < 16; ++f) Pp[f] = __float2bfloat16(g[f]);
    float4* Qp = (float4*)(Q + m * 16);
#pragma unroll
    for (int q = 0; q < 4; ++q)
        Qp[q] = make_float4(g[4 * q], g[4 * q + 1], g[4 * q + 2], g[4 * q + 3]);
}

__global__ __launch_bounds__(256) void k_scatter16_16(const int* __restrict__ edges,
                                                      const bf16* __restrict__ P,
                                                      float* __restrict__ Q,
                                                      int E, int V) {
    int t = blockIdx.x * 256 + threadIdx.x;
    int e = t >> 4;
    if (e >= E) return;
    int f = t & 15;
    int b = blockIdx.y;
    int s = edges[2 * e], d = edges[2 * e + 1];
    float val = b2f(P[((i64)b * V + s) * 16 + f]);
    unsafeAtomicAdd(&Q[((i64)b * V + d) * 16 + f], val);
}

__global__ __launch_bounds__(256) void k_l2_16(const float* __restrict__ W2,
                                               const float* __restrict__ b1,
                                               const float* __restrict__ dinv,
                                               bf16* __restrict__ P, float* __restrict__ Q,
                                               int V) {
    __shared__ float sW[256];
    __shared__ float sb[16];
    sW[threadIdx.x] = W2[threadIdx.x];
    if (threadIdx.x < 16) sb[threadIdx.x] = b1[threadIdx.x];
    __syncthreads();
    int v = blockIdx.x * 256 + threadIdx.x;
    if (v >= V) return;
    i64 m = (i64)blockIdx.y * V + v;
    float di = dinv[v];
    float h[16];
    const float4* Qin = (const float4*)(Q + m * 16);
#pragma unroll
    for (int q = 0; q < 4; ++q) {
        float4 t = Qin[q];
        h[4 * q] = t.x; h[4 * q + 1] = t.y; h[4 * q + 2] = t.z; h[4 * q + 3] = t.w;
    }
#pragma unroll
    for (int k = 0; k < 16; ++k) h[k] = lrelu(di * h[k] + sb[k]);
    float g[16];
#pragma unroll
    for (int f = 0; f < 16; ++f) {
        float a = 0.f;
#pragma unroll
        for (int k = 0; k < 16; ++k) a += h[k] * sW[k * 16 + f];
        g[f] = di * a;
    }
    bf16* Pp = P + m * 16;
#pragma unroll
    for (int f = 0; f < 16; ++f) Pp[f] = __float2bfloat16(g[f]);
    float4* Qp = (float4*)(Q + m * 16);
#pragma unroll
    for (int q = 0; q < 4; ++q)
        Qp[q] = make_float4(g[4 * q], g[4 * q + 1], g[4 * q + 2], g[4 * q + 3]);
}

__global__ __launch_bounds__(256) void k_l3_16(const float* __restrict__ W3,
                                               const float* __restrict__ b2,
                                               const float* __restrict__ dinv,
                                               float* __restrict__ R, float* __restrict__ S,
                                               const float* __restrict__ Q, int V) {
    __shared__ float sW[48];
    __shared__ float sb[16];
    if (threadIdx.x < 48) sW[threadIdx.x] = W3[threadIdx.x];
    if (threadIdx.x < 16) sb[threadIdx.x] = b2[threadIdx.x];
    __syncthreads();
    int v = blockIdx.x * 256 + threadIdx.x;
    if (v >= V) return;
    i64 m = (i64)blockIdx.y * V + v;
    float di = dinv[v];
    float h[16];
    const float4* Qin = (const float4*)(Q + m * 16);
#pragma unroll
    for (int q = 0; q < 4; ++q) {
        float4 t = Qin[q];
        h[4 * q] = t.x; h[4 * q + 1] = t.y; h[4 * q + 2] = t.z; h[4 * q + 3] = t.w;
    }
#pragma unroll
    for (int k = 0; k < 16; ++k) h[k] = lrelu(di * h[k] + sb[k]);
    float g0 = 0.f, g1 = 0.f, g2 = 0.f;
#pragma unroll
    for (int k = 0; k < 16; ++k) {
        g0 += h[k] * sW[k * 3 + 0];
        g1 += h[k] * sW[k * 3 + 1];
        g2 += h[k] * sW[k * 3 + 2];
    }
    float4 t = make_float4(di * g0, di * g1, di * g2, 0.f);
    ((float4*)R)[m] = t;
    ((float4*)S)[m] = t;
}

// ================= generic H path (correctness fallback, H <= 64) =================
__global__ __launch_bounds__(256) void k_l1_g(const float* __restrict__ x,
                                              const float* __restrict__ W1,
                                              const float* __restrict__ dinv,
                                              bf16* __restrict__ P, float* __restrict__ Q,
                                              int b0, int V, int H) {
    extern __shared__ float sW[];
    for (int i = threadIdx.x; i < 3 * H; i += 256) sW[i] = W1[i];
    __syncthreads();
    int v = blockIdx.x * 256 + threadIdx.x;
    if (v >= V) return;
    i64 n = (i64)(b0 + blockIdx.y) * V + v;
    i64 m = (i64)blockIdx.y * V + v;
    float di = dinv[v];
    float x0 = x[n * 3], x1 = x[n * 3 + 1], x2 = x[n * 3 + 2];
    for (int f = 0; f < H; ++f) {
        float g = di * (x0 * sW[f] + x1 * sW[H + f] + x2 * sW[2 * H + f]);
        P[m * H + f] = __float2bfloat16(g);
        Q[m * H + f] = g;
    }
}

__global__ __launch_bounds__(256) void k_scatter_g(const int* __restrict__ edges,
                                                   const bf16* __restrict__ P,
                                                   float* __restrict__ Q,
                                                   int E, int V, int H) {
    int e = blockIdx.x * 256 + threadIdx.x;
    if (e >= E) return;
    int b = blockIdx.y;
    int s = edges[2 * e], d = edges[2 * e + 1];
    for (int f = 0; f < H; ++f)
        unsafeAtomicAdd(&Q[((i64)b * V + d) * H + f], b2f(P[((i64)b * V + s) * H + f]));
}

__global__ __launch_bounds__(256) void k_l2_g(const float* __restrict__ W2,
                                              const float* __restrict__ b1,
                                              const float* __restrict__ dinv,
                                              bf16* __restrict__ P, float* __restrict__ Q,
                                              int V, int H) {
    extern __shared__ float sW[];  // H*H + H
    float* sb = sW + H * H;
    for (int i = threadIdx.x; i < H * H; i += 256) sW[i] = W2[i];
    for (int i = threadIdx.x; i < H; i += 256) sb[i] = b1[i];
    __syncthreads();
    int v = blockIdx.x * 256 + threadIdx.x;
    if (v >= V) return;
    i64 m = (i64)blockIdx.y * V + v;
    float di = dinv[v];
    float h[64];
    for (int k = 0; k < H; ++k) h[k] = lrelu(di * Q[m * H + k] + sb[k]);
    for (int f = 0; f < H; ++f) {
        float a = 0.f;
        for (int k = 0; k < H; ++k) a += h[k] * sW[k * H + f];
        float g = di * a;
        P[m * H + f] = __float2bfloat16(g);
        Q[m * H + f] = g;
    }
}

__global__ __launch_bounds__(256) void k_l3_g(const float* __restrict__ W3,
                                              const float* __restrict__ b2,
                                              const float* __restrict__ dinv,
                                              float* __restrict__ R, float* __restrict__ S,
                                              const float* __restrict__ Q, int V, int H) {
    extern __shared__ float sW[];  // H*3 + H
    float* sb = sW + H * 3;
    for (int i = threadIdx.x; i < H * 3; i += 256) sW[i] = W3[i];
    for (int i = threadIdx.x; i < H; i += 256) sb[i] = b2[i];
    __syncthreads();
    int v = blockIdx.x * 256 + threadIdx.x;
    if (v >= V) return;
    i64 m = (i64)blockIdx.y * V + v;
    float di = dinv[v];
    float g0 = 0.f, g1 = 0.f, g2 = 0.f;
    for (int k = 0; k < H; ++k) {
        float h = lrelu(di * Q[m * H + k] + sb[k]);
        g0 += h * sW[k * 3]; g1 += h * sW[k * 3 + 1]; g2 += h * sW[k * 3 + 2];
    }
    float4 t = make_float4(di * g0, di * g1, di * g2, 0.f);
    ((float4*)R)[m] = t;
    ((float4*)S)[m] = t;
}

// ================= H-independent tail (fp32 outputs!) =================
__global__ __launch_bounds__(256) void k_scatter3(const int* __restrict__ edges,
                                                  const float* __restrict__ R,
                                                  float* __restrict__ S, int E, int V) {
    int e = blockIdx.x * 256 + threadIdx.x;
    if (e >= E) return;
    int b = blockIdx.y;
    int s = edges[2 * e], d = edges[2 * e + 1];
    i64 sn = (i64)b * V + s, dn = (i64)b * V + d;
#pragma unroll
    for (int k = 0; k < 3; ++k) unsafeAtomicAdd(&S[dn * 4 + k], R[sn * 4 + k]);
}

__global__ __launch_bounds__(256) void k_vert(const float* __restrict__ x,
                                              const float* __restrict__ b3,
                                              const float* __restrict__ dinv,
                                              const float* __restrict__ S,
                                              float* __restrict__ Vpos,
                                              float* __restrict__ out0,
                                              int b0, int V, int E) {
    int v = blockIdx.x * 256 + threadIdx.x;
    if (v >= V) return;
    int bg = b0 + blockIdx.y;
    i64 n = (i64)bg * V + v;
    i64 m = (i64)blockIdx.y * V + v;
    float di = dinv[v];
    float4 s = ((const float4*)S)[m];
    float p0 = x[n * 3]     + di * s.x + b3[0];
    float p1 = x[n * 3 + 1] + di * s.y + b3[1];
    float p2 = x[n * 3 + 2] + di * s.z + b3[2];
    ((float4*)Vpos)[m] = make_float4(p0, p1, p2, 0.f);
    i64 o = ((i64)bg * (V + E) + v) * 3;
    out0[o]     = p0;
    out0[o + 1] = p1;
    out0[o + 2] = p2;
}

__global__ __launch_bounds__(256) void k_mid(const int* __restrict__ edges,
                                             const float* __restrict__ Vpos,
                                             float* __restrict__ out0,
                                             int b0, int V, int E) {
    int e = blockIdx.x * 256 + threadIdx.x;
    if (e >= E) return;
    int s = edges[2 * e], d = edges[2 * e + 1];
    float4 ps = ((const float4*)Vpos)[(i64)blockIdx.y * V + s];
    float4 pd = ((const float4*)Vpos)[(i64)blockIdx.y * V + d];
    i64 o = ((i64)(b0 + blockIdx.y) * (V + E) + V + e) * 3;
    out0[o]     = 0.5f * (ps.x + pd.x);
    out0[o + 1] = 0.5f * (ps.y + pd.y);
    out0[o + 2] = 0.5f * (ps.z + pd.z);
}

__global__ __launch_bounds__(256) void k_faces(const int* __restrict__ faces,
                                               float* __restrict__ out1,
                                               i64 F3, i64 faceElems) {
    i64 i = (i64)blockIdx.x * 256 + threadIdx.x;
    if (i >= F3) return;
    i64 o = (i64)blockIdx.y * F3 + i;
    if (o < faceElems) out1[o] = (float)faces[i];
}

extern "C" void kernel_launch(void* const* d_in, const int* in_sizes, int n_in,
                              void* d_out, int out_size, void* d_ws, size_t ws_size,
                              hipStream_t stream) {
    const float* verts = (const float*)d_in[0];
    const int*   edges = (const int*)d_in[1];
    const int*   faces = (const int*)d_in[2];
    const float* W1 = (const float*)d_in[3];
    const float* b1 = (const float*)d_in[4];
    const float* W2 = (const float*)d_in[5];
    const float* b2 = (const float*)d_in[6];
    const float* W3 = (const float*)d_in[7];
    const float* b3 = (const float*)d_in[8];

    // ---- derive actual dims from in_sizes / out_size ----
    const i64 s0 = in_sizes[0];            // 3*B*V
    const i64 E  = in_sizes[1] / 2;
    const i64 F  = in_sizes[2] / 3;
    const int H  = in_sizes[4];            // b1 length
    i64 B = 0;
    const i64 denomB = 3 * (E + F);        // faces broadcast per batch
    if ((i64)out_size > s0 && denomB > 0) {
        i64 Bc = ((i64)out_size - s0) / denomB;
        if (Bc >= 1 && s0 + Bc * denomB == (i64)out_size && s0 % (3 * Bc) == 0) B = Bc;
    }
    if (B == 0) {                          // fallback: faces stored once (not broadcast)
        i64 num = (i64)out_size - s0 - 3 * F;
        if (num > 0 && E > 0 && num % (3 * E) == 0) {
            i64 Bc = num / (3 * E);
            if (Bc >= 1 && s0 % (3 * Bc) == 0) B = Bc;
        }
    }
    if (B == 0) B = 16;                    // last resort
    const i64 V = s0 / (3 * B);

    // ---- workspace layout: chunk CB batches so it provably fits ws_size ----
    const i64 Vp = (V + 255) & ~255LL;
    const size_t AUX = (size_t)Vp * 8;                 // dinv f32 + indeg i32
    const size_t rowB = (size_t)(6 * H + 32) + 64;     // P(2H)+Q(4H)+R(16)+S(16)+slack
    i64 CB = B;
    while (CB > 1 && AUX + (size_t)CB * V * rowB + 4096 > ws_size) CB = (CB + 1) / 2;

    float* ws    = (float*)d_ws;
    float* dinv  = ws;
    int*   indeg = (int*)(ws + Vp);
    char*  base  = (char*)(ws + 2 * Vp);
    auto pad = [](size_t x) { return (x + 255) & ~(size_t)255; };
    bf16*  P = (bf16*)base;
    float* Q = (float*)(base + pad((size_t)CB * V * 2 * H));
    float* R = (float*)((char*)Q + pad((size_t)CB * V * 4 * H));
    float* S = (float*)((char*)R + pad((size_t)CB * V * 16));

    hipMemsetAsync(indeg, 0, V * sizeof(int), stream);
    k_deg<<<dim3((E + 255) / 256), 256, 0, stream>>>(edges, indeg, (int)E);
    k_dinv<<<dim3((V + 255) / 256), 256, 0, stream>>>(indeg, dinv, (int)V);

    float* out0 = (float*)d_out;
    const i64 vertElems = B * (V + E) * 3;
    float* out1 = out0 + vertElems;
    const i64 faceElems = (i64)out_size - vertElems;

    for (i64 b0 = 0; b0 < B; b0 += CB) {
        const i64 CBc = (B - b0 < CB) ? (B - b0) : CB;
        dim3 gn((unsigned)((V + 255) / 256), (unsigned)CBc);
        dim3 ge((unsigned)((E + 255) / 256), (unsigned)CBc);
        if (H == 16) {
            dim3 ge16((unsigned)((E * 16 + 255) / 256), (unsigned)CBc);
            k_l1_16<<<gn, 256, 0, stream>>>(verts, W1, dinv, P, Q, (int)b0, (int)V);
            k_scatter16_16<<<ge16, 256, 0, stream>>>(edges, P, Q, (int)E, (int)V);
            k_l2_16<<<gn, 256, 0, stream>>>(W2, b1, dinv, P, Q, (int)V);
            k_scatter16_16<<<ge16, 256, 0, stream>>>(edges, P, Q, (int)E, (int)V);
            k_l3_16<<<gn, 256, 0, stream>>>(W3, b2, dinv, R, S, Q, (int)V);
        } else {
            size_t sh1 = (size_t)3 * H * 4;
            size_t sh2 = ((size_t)H * H + H) * 4;
            size_t sh3 = ((size_t)H * 3 + H) * 4;
            k_l1_g<<<gn, 256, sh1, stream>>>(verts, W1, dinv, P, Q, (int)b0, (int)V, H);
            k_scatter_g<<<ge, 256, 0, stream>>>(edges, P, Q, (int)E, (int)V, H);
            k_l2_g<<<gn, 256, sh2, stream>>>(W2, b1, dinv, P, Q, (int)V, H);
            k_scatter_g<<<ge, 256, 0, stream>>>(edges, P, Q, (int)E, (int)V, H);
            k_l3_g<<<gn, 256, sh3, stream>>>(W3, b2, dinv, R, S, Q, (int)V, H);
        }
        k_scatter3<<<ge, 256, 0, stream>>>(edges, R, S, (int)E, (int)V);
        k_vert<<<gn, 256, 0, stream>>>(verts, b3, dinv, S, R, out0, (int)b0, (int)V, (int)E);
        k_mid<<<ge, 256, 0, stream>>>(edges, R, out0, (int)b0, (int)V, (int)E);
    }
    const i64 F3 = 3 * F;
    if (faceElems > 0 && F3 > 0)
        k_faces<<<dim3((unsigned)((F3 + 255) / 256), (unsigned)B), 256, 0, stream>>>(
            faces, out1, F3, faceElems);
}